// Round 1
// baseline (215.797 us; speedup 1.0000x reference)
//
#include <hip/hip_runtime.h>

#define LN_EPS 1e-5f

__global__ __launch_bounds__(256) void ln_linear_softmax_kernel(
    const float4* __restrict__ x,     // [n] rows of 4 floats
    const float*  __restrict__ W,     // [4,3] row-major
    const float*  __restrict__ gamma, // [4]
    const float*  __restrict__ beta,  // [4]
    float*        __restrict__ out,   // [n,3]
    int n)
{
    int row = blockIdx.x * blockDim.x + threadIdx.x;
    if (row >= n) return;

    float4 v = x[row];

    // LayerNorm over 4 elements
    float mu = (v.x + v.y + v.z + v.w) * 0.25f;
    float dx = v.x - mu, dy = v.y - mu, dz = v.z - mu, dw = v.w - mu;
    float var = (dx*dx + dy*dy + dz*dz + dw*dw) * 0.25f;
    float rs = rsqrtf(var + LN_EPS);

    float4 g = *(const float4*)gamma;
    float4 b = *(const float4*)beta;
    float h0 = dx * rs * g.x + b.x;
    float h1 = dy * rs * g.y + b.y;
    float h2 = dz * rs * g.z + b.z;
    float h3 = dw * rs * g.w + b.w;

    // W is 4x3 row-major: W[i*3 + j]; load as 3 float4s (12 floats)
    const float4* W4 = (const float4*)W;
    float4 w0 = W4[0]; // W00 W01 W02 W10
    float4 w1 = W4[1]; // W11 W12 W20 W21
    float4 w2 = W4[2]; // W22 W30 W31 W32

    float l0 = h0*w0.x + h1*w0.w + h2*w1.z + h3*w2.y;
    float l1 = h0*w0.y + h1*w1.x + h2*w1.w + h3*w2.z;
    float l2 = h0*w0.z + h1*w1.y + h2*w2.x + h3*w2.w;

    // softmax over 3
    float m  = fmaxf(l0, fmaxf(l1, l2));
    float e0 = __expf(l0 - m);
    float e1 = __expf(l1 - m);
    float e2 = __expf(l2 - m);
    float inv = 1.0f / (e0 + e1 + e2);

    float* o = out + (size_t)row * 3;
    o[0] = e0 * inv;
    o[1] = e1 * inv;
    o[2] = e2 * inv;
}

extern "C" void kernel_launch(void* const* d_in, const int* in_sizes, int n_in,
                              void* d_out, int out_size, void* d_ws, size_t ws_size,
                              hipStream_t stream) {
    const float* x     = (const float*)d_in[0];
    const float* W     = (const float*)d_in[1];
    const float* gamma = (const float*)d_in[2];
    const float* beta  = (const float*)d_in[3];
    float* out = (float*)d_out;

    int n = in_sizes[0] / 4;           // number of rows
    int block = 256;
    int grid = (n + block - 1) / block;
    ln_linear_softmax_kernel<<<grid, block, 0, stream>>>(
        (const float4*)x, W, gamma, beta, out, n);
}

// Round 3
// 213.290 us; speedup vs baseline: 1.0117x; 1.0117x over previous
//
#include <hip/hip_runtime.h>

#define LN_EPS 1e-5f

typedef float v4f __attribute__((ext_vector_type(4)));

constexpr int BLOCK = 256;
constexpr int RPT   = 4;             // rows per thread
constexpr int RPB   = BLOCK * RPT;   // 1024 rows per block

__global__ __launch_bounds__(BLOCK) void ln_linear_softmax_kernel(
    const v4f*   __restrict__ x,     // [n] rows of 4 floats
    const float* __restrict__ W,     // [4,3] row-major
    const float* __restrict__ gamma, // [4]
    const float* __restrict__ beta,  // [4]
    v4f*         __restrict__ out4,  // out viewed as float4 (n*3/4 elements)
    int n)
{
    __shared__ float lds[RPB * 3];    // 12 KB

    const int  tid  = threadIdx.x;
    const long base = (long)blockIdx.x * RPB;

    const v4f g = *(const v4f*)gamma;
    const v4f b = *(const v4f*)beta;
    const v4f* W4 = (const v4f*)W;
    const v4f w0 = W4[0]; // W00 W01 W02 W10
    const v4f w1 = W4[1]; // W11 W12 W20 W21
    const v4f w2 = W4[2]; // W22 W30 W31 W32

    #pragma unroll
    for (int k = 0; k < RPT; ++k) {
        const int  rl  = tid + k * BLOCK;
        const long row = base + rl;
        if (row < n) {
            v4f v = __builtin_nontemporal_load(&x[row]);

            // LayerNorm over 4
            float mu = (v.x + v.y + v.z + v.w) * 0.25f;
            float dx = v.x - mu, dy = v.y - mu, dz = v.z - mu, dw = v.w - mu;
            float var = (dx*dx + dy*dy + dz*dz + dw*dw) * 0.25f;
            float rs  = rsqrtf(var + LN_EPS);

            float h0 = dx * rs * g.x + b.x;
            float h1 = dy * rs * g.y + b.y;
            float h2 = dz * rs * g.z + b.z;
            float h3 = dw * rs * g.w + b.w;

            // h @ W  (4 -> 3)
            float l0 = h0*w0.x + h1*w0.w + h2*w1.z + h3*w2.y;
            float l1 = h0*w0.y + h1*w1.x + h2*w1.w + h3*w2.z;
            float l2 = h0*w0.z + h1*w1.y + h2*w2.x + h3*w2.w;

            // softmax over 3
            float m   = fmaxf(l0, fmaxf(l1, l2));
            float e0  = __expf(l0 - m);
            float e1  = __expf(l1 - m);
            float e2  = __expf(l2 - m);
            float inv = 1.0f / (e0 + e1 + e2);

            // LDS: dword stride 3 -> 2 lanes/bank (free)
            lds[rl*3 + 0] = e0 * inv;
            lds[rl*3 + 1] = e1 * inv;
            lds[rl*3 + 2] = e2 * inv;
        }
    }

    __syncthreads();

    // Cooperative packed store: 768 float4s per block, fully coalesced.
    const v4f* lds4  = (const v4f*)lds;
    const long obase = (long)blockIdx.x * (RPB * 3 / 4);
    const long on4   = ((long)n * 3) / 4;
    #pragma unroll
    for (int k = 0; k < 3; ++k) {
        const long oi = obase + tid + k * BLOCK;
        if (oi < on4) {
            __builtin_nontemporal_store(lds4[tid + k * BLOCK], &out4[oi]);
        }
    }
}

extern "C" void kernel_launch(void* const* d_in, const int* in_sizes, int n_in,
                              void* d_out, int out_size, void* d_ws, size_t ws_size,
                              hipStream_t stream) {
    const float* x     = (const float*)d_in[0];
    const float* W     = (const float*)d_in[1];
    const float* gamma = (const float*)d_in[2];
    const float* beta  = (const float*)d_in[3];
    v4f* out4 = (v4f*)d_out;

    int n = in_sizes[0] / 4;                 // number of rows (8,388,608)
    int grid = (n + RPB - 1) / RPB;          // 8192 blocks
    ln_linear_softmax_kernel<<<grid, BLOCK, 0, stream>>>(
        (const v4f*)x, W, gamma, beta, out4, n);
}